// Round 2
// baseline (147.730 us; speedup 1.0000x reference)
//
#include <hip/hip_runtime.h>
#include <hip/hip_bf16.h>

#define NB 64
#define BATCHES 16
#define ELEMS_PER_BATCH (1024 * 1024)
#define CHUNKS 128                          // blocks per batch
#define CHUNK_ELEMS (ELEMS_PER_BATCH / CHUNKS)   // 8192
#define EPS 1e-8f

__global__ void mi_zero_kernel(unsigned int* __restrict__ hist) {
    int i = threadIdx.x;
    if (i < BATCHES * NB) hist[i] = 0u;
}

__global__ __launch_bounds__(256) void mi_hist_kernel(const float* __restrict__ x,
                                                      const float* __restrict__ y,
                                                      unsigned int* __restrict__ hist) {
    __shared__ unsigned int lh[4][NB];   // per-wave privatized histograms
    const int tid  = threadIdx.x;
    const int wave = tid >> 6;

    // zero LDS hists
    for (int i = tid; i < 4 * NB; i += 256) ((unsigned int*)lh)[i] = 0u;
    __syncthreads();

    const int b     = blockIdx.y;
    const long base = (long)b * ELEMS_PER_BATCH + (long)blockIdx.x * CHUNK_ELEMS;
    const float4* __restrict__ x4 = (const float4*)(x + base);
    const float4* __restrict__ y4 = (const float4*)(y + base);
    const int n4 = CHUNK_ELEMS / 4;      // 2048 float4 per block

    for (int i = tid; i < n4; i += 256) {
        float4 xv = x4[i];
        float4 yv = y4[i];
        #pragma unroll
        for (int c = 0; c < 4; ++c) {
            float xc = (&xv.x)[c];
            float yc = (&yv.x)[c];
            // mul then add with intermediate rounding — matches numpy (no FMA)
            float v = __fadd_rn(__fmul_rn(xc, 64.0f), yc);
            if (v >= 0.0f && v <= 64.0f) {
                int idx = (int)floorf(v);
                if (idx > NB - 1) idx = NB - 1;   // v == 64 -> last bin
                atomicAdd(&lh[wave][idx], 1u);
            }
        }
    }
    __syncthreads();

    for (int i = tid; i < NB; i += 256) {
        unsigned int s = lh[0][i] + lh[1][i] + lh[2][i] + lh[3][i];
        if (s) atomicAdd(&hist[b * NB + i], s);
    }
}

// One block: 16 waves, wave b handles batch b, lane k handles bin k.
__global__ __launch_bounds__(1024) void mi_final_kernel(const unsigned int* __restrict__ hist,
                                                        float* __restrict__ out) {
    const int tid = threadIdx.x;
    const int b   = tid >> 6;
    const int k   = tid & 63;

    float h = (float)hist[b * NB + k];

    // wave-reduce: total count for this batch
    float s = h;
    #pragma unroll
    for (int off = 32; off >= 1; off >>= 1) s += __shfl_xor(s, off, 64);

    float jp = h / s + EPS;

    // p = sum over bins of jp (reference sums joint_prob, ~1 + 64*EPS)
    float p = jp;
    #pragma unroll
    for (int off = 32; off >= 1; off >>= 1) p += __shfl_xor(p, off, 64);

    float term = jp * logf(jp / (p * p));
    float t = term;
    #pragma unroll
    for (int off = 32; off >= 1; off >>= 1) t += __shfl_xor(t, off, 64);

    __shared__ float mi[BATCHES];
    if (k == 0) mi[b] = t;
    __syncthreads();

    if (tid == 0) {
        float acc = 0.0f;
        #pragma unroll
        for (int i = 0; i < BATCHES; ++i) acc += mi[i];
        *out = -acc / (float)BATCHES;
    }
}

extern "C" void kernel_launch(void* const* d_in, const int* in_sizes, int n_in,
                              void* d_out, int out_size, void* d_ws, size_t ws_size,
                              hipStream_t stream) {
    const float* x = (const float*)d_in[0];
    const float* y = (const float*)d_in[1];
    float* out = (float*)d_out;
    unsigned int* hist = (unsigned int*)d_ws;

    mi_zero_kernel<<<1, 1024, 0, stream>>>(hist);

    dim3 grid(CHUNKS, BATCHES);
    mi_hist_kernel<<<grid, 256, 0, stream>>>(x, y, hist);

    mi_final_kernel<<<1, 1024, 0, stream>>>(hist, out);
}